// Round 1
// baseline (958.412 us; speedup 1.0000x reference)
//
#include <hip/hip_runtime.h>
#include <math.h>

// ---------------- problem constants ----------------
constexpr int T_ = 64;
constexpr int H_ = 1024;
constexpr int W_ = 1024;
constexpr int N_ = H_ * W_;
// int((1.0-0.15)*(N-1)) and int(0.3*(N-1)) computed with python double semantics
constexpr unsigned RANK_G = 891288;   // 85th pct index of gm (ascending)
constexpr unsigned RANK_B = 314572;   // 30th pct index of |f|

constexpr int ROWS_PER_BLOCK = 32;
constexpr int BLOCKS_PER_FRAME = H_ / ROWS_PER_BLOCK; // 32

// LDS histogram privatization: 4 copies, +1 word pad so copies land in
// different banks for the same bucket ((i*2049+b)%32 = (i+b)%32).
constexpr int NCOPY = 4;
constexpr int HSZ = 2048 + 1;

// ---------------- workspace layout ----------------
struct WS {
  unsigned int hist[2][T_][2048];   // [q][frame][bucket], q=0:gm q=1:|f|
  unsigned int prefix[2][T_];
  unsigned int rank[2][T_];
  float        thr[2][T_];
  double       acc[T_][4];          // cnt, sum_gm, sum_gm*x, sum_gm*y
};

// Shared gm computation so every pass rounds identically.
__device__ __forceinline__ float gm_at(float cur, float right, float down,
                                       int col, int row) {
  float gx = (col < W_ - 1) ? (right - cur) : 0.0f;
  float gy = (row < H_ - 1) ? (down - cur) : 0.0f;
  return sqrtf(gx * gx + gy * gy);
}

// ---------------- histogram pass (levels 0/1/2) ----------------
__global__ __launch_bounds__(256) void hist_kernel(const float* __restrict__ frames,
                                                   WS* ws, int level) {
  const int t  = blockIdx.y;
  const int r0 = blockIdx.x * ROWS_PER_BLOCK;
  __shared__ unsigned int hg[NCOPY * HSZ];
  __shared__ unsigned int hb[NCOPY * HSZ];
  for (int i = threadIdx.x; i < NCOPY * HSZ; i += 256) { hg[i] = 0; hb[i] = 0; }
  __syncthreads();

  unsigned pg = 0, pb = 0;
  if (level > 0) { pg = ws->prefix[0][t]; pb = ws->prefix[1][t]; }

  const float* f = frames + (size_t)t * N_;
  const int tx = threadIdx.x;
  const int c  = tx * 4;                 // column base, thread covers 4 cols
  const int copyoff = (tx & (NCOPY - 1)) * HSZ;

  for (int r = 0; r < ROWS_PER_BLOCK; ++r) {
    const int h = r0 + r;
    const float* row = f + (size_t)h * W_;
    float4 a = *(const float4*)(row + c);
    float an = (c + 4 < W_) ? row[c + 4] : 0.0f;
    float4 b;
    if (h + 1 < H_) b = *(const float4*)(row + W_ + c);
    else            b = a;               // forces gy = 0
    float xs[5] = {a.x, a.y, a.z, a.w, an};
    float ys[4] = {b.x, b.y, b.z, b.w};
#pragma unroll
    for (int j = 0; j < 4; ++j) {
      float gm = gm_at(xs[j], xs[j + 1], ys[j], c + j, h);
      float bz = fabsf(xs[j]);
      unsigned ug = __float_as_uint(gm);
      unsigned ub = __float_as_uint(bz);
      if (level == 0) {
        atomicAdd(&hg[copyoff + (ug >> 21)], 1u);
        atomicAdd(&hb[copyoff + (ub >> 21)], 1u);
      } else if (level == 1) {
        if ((ug >> 21) == pg) atomicAdd(&hg[copyoff + ((ug >> 10) & 2047u)], 1u);
        if ((ub >> 21) == pb) atomicAdd(&hb[copyoff + ((ub >> 10) & 2047u)], 1u);
      } else {
        if ((ug >> 10) == pg) atomicAdd(&hg[copyoff + (ug & 1023u)], 1u);
        if ((ub >> 10) == pb) atomicAdd(&hb[copyoff + (ub & 1023u)], 1u);
      }
    }
  }
  __syncthreads();
  for (int i = tx; i < 2048; i += 256) {
    unsigned vg = hg[i] + hg[HSZ + i] + hg[2 * HSZ + i] + hg[3 * HSZ + i];
    unsigned vb = hb[i] + hb[HSZ + i] + hb[2 * HSZ + i] + hb[3 * HSZ + i];
    if (vg) atomicAdd(&ws->hist[0][t][i], vg);
    if (vb) atomicAdd(&ws->hist[1][t][i], vb);
  }
}

// ---------------- select pass ----------------
__global__ __launch_bounds__(256) void select_kernel(WS* ws, int level) {
  const int t = blockIdx.x;
  const int q = blockIdx.y;
  const int nb = (level == 2) ? 1024 : 2048;
  unsigned int* hist = ws->hist[q][t];
  __shared__ unsigned partial[256];
  __shared__ unsigned chunk_before[256];
  const int tx = threadIdx.x;
  const int per = nb / 256;              // 8 or 4
  unsigned sum = 0;
  for (int j = 0; j < per; ++j) sum += hist[tx * per + j];
  partial[tx] = sum;
  __syncthreads();
  if (tx == 0) {
    unsigned cum = 0;
    for (int i = 0; i < 256; ++i) { chunk_before[i] = cum; cum += partial[i]; }
  }
  __syncthreads();
  unsigned r = (level == 0) ? (q == 0 ? RANK_G : RANK_B) : ws->rank[q][t];
  unsigned cb = chunk_before[tx];
  if (r >= cb && r < cb + partial[tx]) {   // exactly one thread
    unsigned rem = r - cb;
    unsigned cum = 0;
    int bucket = 0;
    for (int j = 0; j < per; ++j) {
      unsigned hv = hist[tx * per + j];
      if (rem < cum + hv) { bucket = tx * per + j; rem -= cum; break; }
      cum += hv;
    }
    if (level == 0) {
      ws->prefix[q][t] = (unsigned)bucket;
      ws->rank[q][t]   = rem;
    } else if (level == 1) {
      ws->prefix[q][t] = (ws->prefix[q][t] << 11) | (unsigned)bucket;
      ws->rank[q][t]   = rem;
    } else {
      unsigned u = (ws->prefix[q][t] << 10) | (unsigned)bucket;
      ws->thr[q][t] = __uint_as_float(u);
    }
  }
  __syncthreads();
  for (int i = tx; i < 2048; i += 256) hist[i] = 0;   // ready for next level
}

// ---------------- masked stats pass ----------------
__global__ __launch_bounds__(256) void stats_kernel(const float* __restrict__ frames,
                                                    WS* ws) {
  const int t  = blockIdx.y;
  const int r0 = blockIdx.x * ROWS_PER_BLOCK;
  const float thrg = ws->thr[0][t];
  const float thrb = ws->thr[1][t];
  const float* f = frames + (size_t)t * N_;
  const int tx = threadIdx.x;
  const int c  = tx * 4;

  float cnt = 0.f, sgm = 0.f, swx = 0.f, swy = 0.f;
  for (int r = 0; r < ROWS_PER_BLOCK; ++r) {
    const int h = r0 + r;
    const float* row = f + (size_t)h * W_;
    float4 a = *(const float4*)(row + c);
    float an = (c + 4 < W_) ? row[c + 4] : 0.0f;
    float4 b;
    if (h + 1 < H_) b = *(const float4*)(row + W_ + c);
    else            b = a;
    float xs[5] = {a.x, a.y, a.z, a.w, an};
    float ys[4] = {b.x, b.y, b.z, b.w};
#pragma unroll
    for (int j = 0; j < 4; ++j) {
      float gm = gm_at(xs[j], xs[j + 1], ys[j], c + j, h);
      float bz = fabsf(xs[j]);
      if (gm > thrg && bz < thrb) {
        cnt += 1.0f;
        sgm += gm;
        swx += gm * (float)(c + j);
        swy += gm * (float)h;
      }
    }
  }
  // wave(64) reduce then cross-wave via LDS
  for (int off = 32; off; off >>= 1) {
    cnt += __shfl_down(cnt, off);
    sgm += __shfl_down(sgm, off);
    swx += __shfl_down(swx, off);
    swy += __shfl_down(swy, off);
  }
  __shared__ double pc[4], pg[4], px[4], py[4];
  const int wave = tx >> 6;
  if ((tx & 63) == 0) { pc[wave] = cnt; pg[wave] = sgm; px[wave] = swx; py[wave] = swy; }
  __syncthreads();
  if (tx == 0) {
    atomicAdd(&ws->acc[t][0], pc[0] + pc[1] + pc[2] + pc[3]);
    atomicAdd(&ws->acc[t][1], pg[0] + pg[1] + pg[2] + pg[3]);
    atomicAdd(&ws->acc[t][2], px[0] + px[1] + px[2] + px[3]);
    atomicAdd(&ws->acc[t][3], py[0] + py[1] + py[2] + py[3]);
  }
}

// ---------------- finalize: per-frame stats -> conv -> 8 scalars ----------------
__global__ __launch_bounds__(64) void finalize_kernel(WS* ws,
                                                      const float* __restrict__ conv_w,
                                                      const float* __restrict__ conv_b,
                                                      float* __restrict__ out) {
  __shared__ float st[T_][4];
  __shared__ float s[T_][4];
  const int tx = threadIdx.x;
  if (tx < T_) {
    double cnt = ws->acc[tx][0];
    double sgm = ws->acc[tx][1];
    double swx = ws->acc[tx][2];
    double swy = ws->acc[tx][3];
    float pil  = fmaxf((float)cnt, 1e-6f);
    float wsum = fmaxf((float)sgm, 1e-6f);
    st[tx][0] = pil / (float)N_;                   // length
    st[tx][1] = (float)sgm / pil;                  // intensity
    st[tx][2] = (float)swx / wsum / (float)W_;     // x_cent
    st[tx][3] = (float)swy / wsum / (float)H_;     // y_cent
  }
  __syncthreads();
  if (tx < T_) {
#pragma unroll
    for (int c2 = 0; c2 < 4; ++c2) {
      float acc = conv_b[c2];
#pragma unroll
      for (int k = 0; k < 3; ++k) {
        int ti = tx + k - 1;
        if (ti >= 0 && ti < T_) acc += conv_w[c2 * 3 + k] * st[ti][c2];
      }
      s[tx][c2] = acc;
    }
  }
  __syncthreads();
  if (tx == 0) {
    float lm = 0.f, im = 0.f;
    for (int i = 0; i < T_; ++i) { lm += s[i][0]; im += s[i][1]; }
    lm /= (float)T_; im /= (float)T_;
    float lt = 0.f, it = 0.f;
    for (int i = 0; i < T_; ++i) {
      float tn = (float)i / (float)(T_ - 1) - 0.5f;
      lt += (s[i][0] - lm) * tn;
      it += (s[i][1] - im) * tn;
    }
    lt *= 6.0f / (float)T_;
    it *= 6.0f / (float)T_;
    float speeds[T_ - 1];
    float spsum = 0.f, sdx = 0.f, sdy = 0.f;
    for (int i = 0; i < T_ - 1; ++i) {
      float dx = s[i + 1][2] - s[i][2];
      float dy = s[i + 1][3] - s[i][3];
      float sp = sqrtf(dx * dx + dy * dy);
      speeds[i] = sp; spsum += sp; sdx += dx; sdy += dy;
    }
    float ms  = spsum / (float)(T_ - 1);
    float dir = atan2f(sdy, sdx) / 3.14159265358979323846f;
    float gr  = (s[T_ - 1][0] - s[0][0]) / (float)(T_ - 1);
    float var = 0.f;
    for (int i = 0; i < T_ - 1; ++i) { float d = speeds[i] - ms; var += d * d; }
    float inst = sqrtf(var / (float)(T_ - 2));   // ddof=1 over 63 samples
    out[0] = lm; out[1] = lt; out[2] = im; out[3] = it;
    out[4] = ms; out[5] = dir; out[6] = gr; out[7] = inst;
  }
}

// ---------------- launch ----------------
extern "C" void kernel_launch(void* const* d_in, const int* in_sizes, int n_in,
                              void* d_out, int out_size, void* d_ws, size_t ws_size,
                              hipStream_t stream) {
  const float* frames = (const float*)d_in[0];
  // d_in[1] = observed_mask (all true, unused by reference math)
  const float* conv_w = (const float*)d_in[2];
  const float* conv_b = (const float*)d_in[3];
  float* out = (float*)d_out;
  WS* ws = (WS*)d_ws;

  hipMemsetAsync(d_ws, 0, sizeof(WS), stream);

  dim3 grid(BLOCKS_PER_FRAME, T_);
  hist_kernel<<<grid, 256, 0, stream>>>(frames, ws, 0);
  select_kernel<<<dim3(T_, 2), 256, 0, stream>>>(ws, 0);
  hist_kernel<<<grid, 256, 0, stream>>>(frames, ws, 1);
  select_kernel<<<dim3(T_, 2), 256, 0, stream>>>(ws, 1);
  hist_kernel<<<grid, 256, 0, stream>>>(frames, ws, 2);
  select_kernel<<<dim3(T_, 2), 256, 0, stream>>>(ws, 2);
  stats_kernel<<<grid, 256, 0, stream>>>(frames, ws);
  finalize_kernel<<<1, 64, 0, stream>>>(ws, conv_w, conv_b, out);
}